// Round 1
// baseline (98.989 us; speedup 1.0000x reference)
//
#include <hip/hip_runtime.h>
#include <math.h>

#define BATCH 64
#define HH 240
#define WW 320
#define HWTOT 76800
#define SPLIT 32
#define HW4 19200      // HWTOT/4
#define SLICE4 600     // HW4/SPLIT
#define KS 96
#define NSLICE 200

// ---------------- JtR = Jt @ (weights * R) ----------------
// grid: BATCH*SPLIT blocks x 256. Each block reduces a 2400-elem slice for all
// 6 rows simultaneously (reads w,R once). float4 coalesced loads.
__global__ __launch_bounds__(256) void k_jtr_partial(
    const float* __restrict__ Jt, const float* __restrict__ wgt,
    const float* __restrict__ Rin, float* __restrict__ part) {
  int b = blockIdx.x / SPLIT, s = blockIdx.x % SPLIT;
  const float4* w4 = (const float4*)(wgt + (size_t)b * HWTOT);
  const float4* r4 = (const float4*)(Rin + (size_t)b * HWTOT);
  const float4* j4 = (const float4*)(Jt + (size_t)b * 6 * HWTOT);
  float acc[6] = {0.f, 0.f, 0.f, 0.f, 0.f, 0.f};
  int end = (s + 1) * SLICE4;
  for (int t = s * SLICE4 + (int)threadIdx.x; t < end; t += 256) {
    float4 wv = w4[t], rv = r4[t];
    float4 p;
    p.x = wv.x * rv.x; p.y = wv.y * rv.y; p.z = wv.z * rv.z; p.w = wv.w * rv.w;
#pragma unroll
    for (int i = 0; i < 6; ++i) {
      float4 jv = j4[i * HW4 + t];
      acc[i] += jv.x * p.x + jv.y * p.y + jv.z * p.z + jv.w * p.w;
    }
  }
#pragma unroll
  for (int i = 0; i < 6; ++i) {
    float v = acc[i];
    for (int off = 32; off; off >>= 1) v += __shfl_down(v, off, 64);
    acc[i] = v;
  }
  __shared__ float sred[4][6];
  int lane = threadIdx.x & 63, wid = threadIdx.x >> 6;
  if (lane == 0) {
#pragma unroll
    for (int i = 0; i < 6; ++i) sred[wid][i] = acc[i];
  }
  __syncthreads();
  if (threadIdx.x < 6) {
    float v = sred[0][threadIdx.x] + sred[1][threadIdx.x] +
              sred[2][threadIdx.x] + sred[3][threadIdx.x];
    part[(b * SPLIT + s) * 6 + threadIdx.x] = v;
  }
}

__global__ void k_jtr_reduce(const float* __restrict__ part, float* __restrict__ JtR) {
  int o = threadIdx.x;  // b*6+i
  if (o < BATCH * 6) {
    int b = o / 6, i = o % 6;
    float v = 0.f;
    for (int s = 0; s < SPLIT; ++s) v += part[(b * SPLIT + s) * 6 + i];
    JtR[o] = v;
  }
}

// ---------------- maxpool2 of R: [B,240,320] -> [B,120,160] ----------------
__global__ void k_pool1(const float* __restrict__ Rin, float* __restrict__ Rp) {
  int o = blockIdx.x * 256 + threadIdx.x;
  if (o >= BATCH * 120 * 160) return;
  int x = o % 160, y = (o / 160) % 120, b = o / (160 * 120);
  const float* r = Rin + (size_t)b * HWTOT + (2 * y) * WW + 2 * x;
  Rp[o] = fmaxf(fmaxf(r[0], r[1]), fmaxf(r[WW], r[WW + 1]));
}

// ---------------- weight repack ----------------
// conv1_w [8][1][3][3] -> w1r [tap][oc]  (9*8)
// conv2_w [16][8][3][3] -> w2r [ic][tap][oc] (8*9*16)
__global__ void k_repack(const float* __restrict__ c1w, const float* __restrict__ c2w,
                         float* __restrict__ w1r, float* __restrict__ w2r) {
  int o = blockIdx.x * 256 + threadIdx.x;
  if (o < 72) { int oc = o / 9, tap = o % 9; w1r[tap * 8 + oc] = c1w[o]; }
  if (o < 1152) {
    int oc = o / 72, ic = (o / 9) % 8, tap = o % 9;
    w2r[(ic * 9 + tap) * 16 + oc] = c2w[o];
  }
}

// ---------------- conv1(1->8,3x3,same)+relu+maxpool fused ----------------
// in Rp [B,120,160], out h1 [B,8,60,80]. grid (5,4,B), block 256 (16x16 pooled tile)
__global__ __launch_bounds__(256) void k_conv1(
    const float* __restrict__ Rp, const float* __restrict__ w1r,
    const float* __restrict__ bias, float* __restrict__ h1) {
  __shared__ float sA[34][37];
  __shared__ float sW[72];
  __shared__ float sB[8];
  int b = blockIdx.z, ty0 = blockIdx.y * 16, tx0 = blockIdx.x * 16;
  int tid = threadIdx.x;
  if (tid < 72) sW[tid] = w1r[tid];
  if (tid < 8) sB[tid] = bias[tid];
  int iy0 = ty0 * 2 - 1, ix0 = tx0 * 2 - 1;
  const float* src = Rp + (size_t)b * 120 * 160;
  for (int idx = tid; idx < 34 * 34; idx += 256) {
    int r = idx / 34, c = idx % 34;
    int gy = iy0 + r, gx = ix0 + c;
    float v = 0.f;
    if (gy >= 0 && gy < 120 && gx >= 0 && gx < 160) v = src[gy * 160 + gx];
    sA[r][c] = v;
  }
  __syncthreads();
  int ly = tid / 16, lx = tid % 16;
  int y = ty0 + ly, x = tx0 + lx;
  float win[16];
#pragma unroll
  for (int r = 0; r < 4; ++r)
#pragma unroll
    for (int c = 0; c < 4; ++c) win[r * 4 + c] = sA[2 * ly + r][2 * lx + c];
  float acc[8][4];
#pragma unroll
  for (int oc = 0; oc < 8; ++oc)
#pragma unroll
    for (int p = 0; p < 4; ++p) acc[oc][p] = 0.f;
#pragma unroll
  for (int tap = 0; tap < 9; ++tap) {
    int ky = tap / 3, kx = tap % 3;
#pragma unroll
    for (int oc = 0; oc < 8; ++oc) {
      float wv = sW[tap * 8 + oc];
#pragma unroll
      for (int py = 0; py < 2; ++py)
#pragma unroll
        for (int px = 0; px < 2; ++px)
          acc[oc][py * 2 + px] += wv * win[(py + ky) * 4 + (px + kx)];
    }
  }
  if (y < 60) {
#pragma unroll
    for (int oc = 0; oc < 8; ++oc) {
      float m = fmaxf(fmaxf(acc[oc][0], acc[oc][1]), fmaxf(acc[oc][2], acc[oc][3])) + sB[oc];
      h1[(((size_t)b * 8 + oc) * 60 + y) * 80 + x] = fmaxf(m, 0.f);
    }
  }
}

// ---------------- conv2(8->16,3x3,same)+relu+maxpool fused ----------------
// in h1 [B,8,60,80], out h2 [B,16,30,40]. grid (3,2,B*2) (z = b*2+ocgroup)
__global__ __launch_bounds__(256) void k_conv2(
    const float* __restrict__ h1, const float* __restrict__ w2r,
    const float* __restrict__ bias, float* __restrict__ h2) {
  __shared__ float sA[8][34][37];
  __shared__ __align__(16) float sW[576];  // [ic][tap][8oc of this group]
  __shared__ float sB[8];
  int b = blockIdx.z >> 1, ocg = blockIdx.z & 1;
  int ty0 = blockIdx.y * 16, tx0 = blockIdx.x * 16;
  int tid = threadIdx.x;
  for (int i = tid; i < 576; i += 256) {
    int ictap = i / 8, o = i % 8;
    sW[i] = w2r[ictap * 16 + ocg * 8 + o];
  }
  if (tid < 8) sB[tid] = bias[ocg * 8 + tid];
  int iy0 = ty0 * 2 - 1, ix0 = tx0 * 2 - 1;
  const float* src = h1 + (size_t)b * 8 * 60 * 80;
  for (int idx = tid; idx < 8 * 34 * 34; idx += 256) {
    int ic = idx / (34 * 34), rc = idx % (34 * 34);
    int r = rc / 34, c = rc % 34;
    int gy = iy0 + r, gx = ix0 + c;
    float v = 0.f;
    if (gy >= 0 && gy < 60 && gx >= 0 && gx < 80) v = src[(ic * 60 + gy) * 80 + gx];
    sA[ic][r][c] = v;
  }
  __syncthreads();
  int ly = tid / 16, lx = tid % 16;
  int y = ty0 + ly, x = tx0 + lx;
  float acc[8][4];
#pragma unroll
  for (int oc = 0; oc < 8; ++oc)
#pragma unroll
    for (int p = 0; p < 4; ++p) acc[oc][p] = 0.f;
  const float4* sW4 = (const float4*)sW;
#pragma unroll 1
  for (int ic = 0; ic < 8; ++ic) {
    float win[16];
#pragma unroll
    for (int r = 0; r < 4; ++r)
#pragma unroll
      for (int c = 0; c < 4; ++c) win[r * 4 + c] = sA[ic][2 * ly + r][2 * lx + c];
#pragma unroll
    for (int tap = 0; tap < 9; ++tap) {
      int ky = tap / 3, kx = tap % 3;
#pragma unroll
      for (int q = 0; q < 2; ++q) {
        float4 w4v = sW4[(ic * 9 + tap) * 2 + q];
        float warr[4] = {w4v.x, w4v.y, w4v.z, w4v.w};
#pragma unroll
        for (int c4 = 0; c4 < 4; ++c4) {
          float wv = warr[c4];
          int oc = q * 4 + c4;
#pragma unroll
          for (int py = 0; py < 2; ++py)
#pragma unroll
            for (int px = 0; px < 2; ++px)
              acc[oc][py * 2 + px] += wv * win[(py + ky) * 4 + (px + kx)];
        }
      }
    }
  }
  if (y < 30 && x < 40) {
#pragma unroll
    for (int o = 0; o < 8; ++o) {
      int oc = ocg * 8 + o;
      float m = fmaxf(fmaxf(acc[o][0], acc[o][1]), fmaxf(acc[o][2], acc[o][3])) + sB[o];
      h2[(((size_t)b * 16 + oc) * 30 + y) * 40 + x] = fmaxf(m, 0.f);
    }
  }
}

// ---------------- fc1: [64,19200] x [64,19200]^T, K-split partial GEMM ----------------
__global__ __launch_bounds__(256) void k_fc1_part(
    const float* __restrict__ h2, const float* __restrict__ f1w,
    float* __restrict__ part) {
  __shared__ __align__(16) float sH[KS * 68];
  __shared__ __align__(16) float sWt[KS * 68];
  int sl = blockIdx.x, k0 = sl * KS;
  int tid = threadIdx.x;
  for (int idx = tid; idx < 64 * KS; idx += 256) {
    int b = idx / KS, kk = idx % KS;
    sH[kk * 68 + b] = h2[(size_t)b * 19200 + k0 + kk];
    sWt[kk * 68 + b] = f1w[(size_t)b * 19200 + k0 + kk];  // b plays the j role
  }
  __syncthreads();
  int bq = tid % 16, jq = tid / 16;
  int b0 = bq * 4, j0 = jq * 4;
  float acc[4][4];
#pragma unroll
  for (int i = 0; i < 4; ++i)
#pragma unroll
    for (int j = 0; j < 4; ++j) acc[i][j] = 0.f;
  for (int kk = 0; kk < KS; ++kk) {
    float4 hv = *(const float4*)&sH[kk * 68 + b0];
    float4 wv = *(const float4*)&sWt[kk * 68 + j0];
    float hb[4] = {hv.x, hv.y, hv.z, hv.w};
    float wb[4] = {wv.x, wv.y, wv.z, wv.w};
#pragma unroll
    for (int i = 0; i < 4; ++i)
#pragma unroll
      for (int j = 0; j < 4; ++j) acc[i][j] += hb[i] * wb[j];
  }
#pragma unroll
  for (int i = 0; i < 4; ++i)
#pragma unroll
    for (int j = 0; j < 4; ++j)
      part[(size_t)sl * 4096 + (b0 + i) * 64 + (j0 + j)] = acc[i][j];
}

__global__ void k_fc1_reduce(const float* __restrict__ part, const float* __restrict__ bias,
                             float* __restrict__ fc1out) {
  int o = blockIdx.x * 256 + threadIdx.x;
  if (o >= 4096) return;
  float v = 0.f;
  for (int s = 0; s < NSLICE; ++s) v += part[(size_t)s * 4096 + o];
  v += bias[o % 64];
  fc1out[o] = fmaxf(v, 0.f);
}

// ---------------- fc2 + softmax + consts + sigmoid -> lambda ----------------
__global__ void k_head(const float* __restrict__ fc1out, const float* __restrict__ f2w,
                       const float* __restrict__ f2b, const float* __restrict__ consts,
                       float* __restrict__ lam) {
  int b = threadIdx.x;
  if (b >= BATCH) return;
  float l[6];
#pragma unroll
  for (int i = 0; i < 6; ++i) {
    float v = f2b[i];
    for (int k = 0; k < 64; ++k) v += fc1out[b * 64 + k] * f2w[i * 64 + k];
    l[i] = v;
  }
  float m = l[0];
#pragma unroll
  for (int i = 1; i < 6; ++i) m = fmaxf(m, l[i]);
  float e[6], s = 0.f;
#pragma unroll
  for (int i = 0; i < 6; ++i) { e[i] = expf(l[i] - m); s += e[i]; }
  float inv = 1.f / s;
#pragma unroll
  for (int j = 0; j < 6; ++j) {
    float wc = 0.f;
#pragma unroll
    for (int i = 0; i < 6; ++i) wc += (e[i] * inv) * consts[i * 6 + j];
    float sg = 1.f / (1.f + expf(-wc));
    lam[b * 6 + j] = expf((-6.f + sg) * 2.302585092994046f);  // 10^(-6+sg)
  }
}

// ---------------- damped 6x6 solve + Rodrigues + pose compose ----------------
__global__ void k_solve(const float* __restrict__ JtJ, const float* __restrict__ JtRv,
                        const float* __restrict__ lam, const float* __restrict__ poseR,
                        const float* __restrict__ poseT, float* __restrict__ out) {
  int b = threadIdx.x;
  if (b >= BATCH) return;
  float Hm[6][6];
  const float* src = JtJ + b * 36;
  float tr = 0.f;
#pragma unroll
  for (int i = 0; i < 6; ++i) {
#pragma unroll
    for (int j = 0; j < 6; ++j) Hm[i][j] = src[i * 6 + j];
    tr += src[i * 6 + i];
  }
  float rhs[6];
#pragma unroll
  for (int i = 0; i < 6; ++i) {
    rhs[i] = JtRv[b * 6 + i];
    Hm[i][i] += lam[b * 6 + i] + 1e-6f * tr + 1e-6f;
  }
  // Cholesky (H is SPD: A@A^T + 6I + positive diag), fully unrolled
  float L[6][6];
#pragma unroll
  for (int i = 0; i < 6; ++i) {
#pragma unroll
    for (int j = 0; j < 6; ++j) {
      if (j > i) continue;
      float s = Hm[i][j];
#pragma unroll
      for (int k = 0; k < 6; ++k)
        if (k < j) s -= L[i][k] * L[j][k];
      if (i == j) L[i][j] = sqrtf(fmaxf(s, 1e-30f));
      else L[i][j] = s / L[j][j];
    }
  }
  float y[6];
#pragma unroll
  for (int i = 0; i < 6; ++i) {
    float s = rhs[i];
#pragma unroll
    for (int k = 0; k < 6; ++k)
      if (k < i) s -= L[i][k] * y[k];
    y[i] = s / L[i][i];
  }
  float xi[6];
#pragma unroll
  for (int ii = 5; ii >= 0; --ii) {
    float s = y[ii];
#pragma unroll
    for (int k = 0; k < 6; ++k)
      if (k > ii) s -= L[k][ii] * xi[k];
    xi[ii] = s / L[ii][ii];
  }
  // Rodrigues on w = -xi[:3]
  float wx = -xi[0], wy = -xi[1], wz = -xi[2];
  float th = fmaxf(sqrtf(wx * wx + wy * wy + wz * wz), 1e-12f);
  float ux = wx / th, uy = wy / th, uz = wz / th;
  float s = sinf(th), c1 = 1.f - cosf(th);
  float Rd[3][3];
  Rd[0][0] = 1.f + c1 * (ux * ux - 1.f);
  Rd[0][1] = -s * uz + c1 * (ux * uy);
  Rd[0][2] = s * uy + c1 * (ux * uz);
  Rd[1][0] = s * uz + c1 * (uy * ux);
  Rd[1][1] = 1.f + c1 * (uy * uy - 1.f);
  Rd[1][2] = -s * ux + c1 * (uy * uz);
  Rd[2][0] = -s * uy + c1 * (uz * ux);
  Rd[2][1] = s * ux + c1 * (uz * uy);
  Rd[2][2] = 1.f + c1 * (uz * uz - 1.f);
  float dt[3];
#pragma unroll
  for (int r = 0; r < 3; ++r)
    dt[r] = -(Rd[r][0] * xi[3] + Rd[r][1] * xi[4] + Rd[r][2] * xi[5]);
  const float* pR = poseR + b * 9;
  const float* pt = poseT + b * 3;
#pragma unroll
  for (int r = 0; r < 3; ++r) {
#pragma unroll
    for (int cc = 0; cc < 3; ++cc) {
      out[b * 12 + r * 4 + cc] =
          pR[r * 3 + 0] * Rd[0][cc] + pR[r * 3 + 1] * Rd[1][cc] + pR[r * 3 + 2] * Rd[2][cc];
    }
    out[b * 12 + r * 4 + 3] =
        pR[r * 3 + 0] * dt[0] + pR[r * 3 + 1] * dt[1] + pR[r * 3 + 2] * dt[2] + pt[r];
  }
}

extern "C" void kernel_launch(void* const* d_in, const int* in_sizes, int n_in,
                              void* d_out, int out_size, void* d_ws, size_t ws_size,
                              hipStream_t stream) {
  const float* JtJ = (const float*)d_in[0];
  const float* Jt = (const float*)d_in[1];
  const float* wts = (const float*)d_in[2];
  const float* Rin = (const float*)d_in[3];
  const float* poseR = (const float*)d_in[4];
  const float* poseT = (const float*)d_in[5];
  const float* consts = (const float*)d_in[11];
  const float* c1w = (const float*)d_in[12];
  const float* c1b = (const float*)d_in[13];
  const float* c2w = (const float*)d_in[14];
  const float* c2b = (const float*)d_in[15];
  const float* f1w = (const float*)d_in[16];
  const float* f1b = (const float*)d_in[17];
  const float* f2w = (const float*)d_in[18];
  const float* f2b = (const float*)d_in[19];
  float* ws = (float*)d_ws;
  float* part = ws;                   // 12288
  float* JtRv = part + 12288;         // 384
  float* Rp = JtRv + 384;             // 1228800
  float* h1 = Rp + 1228800;           // 2457600
  float* h2 = h1 + 2457600;           // 1228800
  float* w1r = h2 + 1228800;          // 72 (padded 128)
  float* w2r = w1r + 128;             // 1152
  float* fcpart = w2r + 1152;         // 819200
  float* fc1out = fcpart + 819200;    // 4096
  float* lam = fc1out + 4096;         // 384
  float* out = (float*)d_out;

  k_jtr_partial<<<dim3(BATCH * SPLIT), dim3(256), 0, stream>>>(Jt, wts, Rin, part);
  k_pool1<<<dim3((BATCH * 120 * 160 + 255) / 256), dim3(256), 0, stream>>>(Rin, Rp);
  k_repack<<<dim3(5), dim3(256), 0, stream>>>(c1w, c2w, w1r, w2r);
  k_jtr_reduce<<<dim3(1), dim3(384), 0, stream>>>(part, JtRv);
  k_conv1<<<dim3(5, 4, BATCH), dim3(256), 0, stream>>>(Rp, w1r, c1b, h1);
  k_conv2<<<dim3(3, 2, BATCH * 2), dim3(256), 0, stream>>>(h1, w2r, c2b, h2);
  k_fc1_part<<<dim3(NSLICE), dim3(256), 0, stream>>>(h2, f1w, fcpart);
  k_fc1_reduce<<<dim3(16), dim3(256), 0, stream>>>(fcpart, f1b, fc1out);
  k_head<<<dim3(1), dim3(64), 0, stream>>>(fc1out, f2w, f2b, consts, lam);
  k_solve<<<dim3(1), dim3(64), 0, stream>>>(JtJ, JtRv, lam, poseR, poseT, out);
}

// Round 2
// 88.263 us; speedup vs baseline: 1.1215x; 1.1215x over previous
//
#include <hip/hip_runtime.h>
#include <math.h>

#define BATCH 64
#define WW 320
#define HWTOT 76800
#define SPLIT 32
#define NJTR 2048      // BATCH*SPLIT
#define HW4 19200      // HWTOT/4
#define SLICE4 600     // HW4/SPLIT
#define KS 96
#define NSLICE 200

// ================= K1: jtr partials (blocks<NJTR) + fused pool+conv1 =================
__global__ __launch_bounds__(256) void k_front(
    const float* __restrict__ Jt, const float* __restrict__ wgt,
    const float* __restrict__ Rin, const float* __restrict__ c1w,
    const float* __restrict__ c1b, float* __restrict__ part,
    float* __restrict__ h1) {
  __shared__ float smem[34 * 37 + 96];
  int tid = threadIdx.x;
  if (blockIdx.x < NJTR) {
    // ---- JtR partial: block reduces a 2400-elem slice for all 6 rows ----
    int b = blockIdx.x / SPLIT, s = blockIdx.x % SPLIT;
    const float4* w4 = (const float4*)(wgt + (size_t)b * HWTOT);
    const float4* r4 = (const float4*)(Rin + (size_t)b * HWTOT);
    const float4* j4 = (const float4*)(Jt + (size_t)b * 6 * HWTOT);
    float acc[6] = {0.f, 0.f, 0.f, 0.f, 0.f, 0.f};
    int end = (s + 1) * SLICE4;
    for (int t = s * SLICE4 + tid; t < end; t += 256) {
      float4 wv = w4[t], rv = r4[t];
      float4 p;
      p.x = wv.x * rv.x; p.y = wv.y * rv.y; p.z = wv.z * rv.z; p.w = wv.w * rv.w;
#pragma unroll
      for (int i = 0; i < 6; ++i) {
        float4 jv = j4[i * HW4 + t];
        acc[i] += jv.x * p.x + jv.y * p.y + jv.z * p.z + jv.w * p.w;
      }
    }
#pragma unroll
    for (int i = 0; i < 6; ++i) {
      float v = acc[i];
      for (int off = 32; off; off >>= 1) v += __shfl_down(v, off, 64);
      acc[i] = v;
    }
    float* sred = smem;  // [4][6]
    int lane = tid & 63, wid = tid >> 6;
    if (lane == 0) {
#pragma unroll
      for (int i = 0; i < 6; ++i) sred[wid * 6 + i] = acc[i];
    }
    __syncthreads();
    if (tid < 6) {
      part[(b * SPLIT + s) * 6 + tid] =
          sred[0 + tid] + sred[6 + tid] + sred[12 + tid] + sred[18 + tid];
    }
    return;
  }
  // ---- fused maxpool2(R) + conv1(1->8) + relu + maxpool2 -> h1[B,8,60,80] ----
  int cb = blockIdx.x - NJTR;            // 0..1279
  int b = cb / 20, rem = cb % 20;
  int by = rem / 5, bx = rem % 5;
  float (*sA)[37] = (float(*)[37])smem;  // [34][37] pooled input tile (+1 col offset)
  float* sW = smem + 34 * 37;            // [9][8]
  float* sB = sW + 72;
  if (tid < 72) sW[tid] = c1w[(tid % 8) * 9 + tid / 8];  // [tap][oc] <- [oc][tap]
  if (tid < 8) sB[tid] = c1b[tid];
  int iy0 = 32 * by - 1;                 // pooled row of sA[0]
  const float* src = Rin + (size_t)b * HWTOT;
  // stage: 34 pooled rows x 36 pooled cols (cols start at 32*bx-2), aligned float4 loads
  for (int idx = tid; idx < 34 * 18; idx += 256) {
    int pr = idx / 18, c4 = idx % 18;
    int py = iy0 + pr;
    int gx = 64 * bx - 4 + 4 * c4;
    float cell0 = 0.f, cell1 = 0.f;
    if (py >= 0 && py < 120 && gx >= 0 && gx < 320) {
      const float4* row0 = (const float4*)(src + (size_t)(2 * py) * WW + gx);
      const float4* row1 = (const float4*)(src + (size_t)(2 * py + 1) * WW + gx);
      float4 v0 = row0[0], v1 = row1[0];
      cell0 = fmaxf(fmaxf(v0.x, v0.y), fmaxf(v1.x, v1.y));
      cell1 = fmaxf(fmaxf(v0.z, v0.w), fmaxf(v1.z, v1.w));
    }
    sA[pr][2 * c4] = cell0;
    sA[pr][2 * c4 + 1] = cell1;
  }
  __syncthreads();
  int ly = tid / 16, lx = tid % 16;
  int y = 16 * by + ly, x = 16 * bx + lx;
  float win[16];
#pragma unroll
  for (int r = 0; r < 4; ++r)
#pragma unroll
    for (int c = 0; c < 4; ++c) win[r * 4 + c] = sA[2 * ly + r][2 * lx + c + 1];
  float acc[8][4];
#pragma unroll
  for (int oc = 0; oc < 8; ++oc)
#pragma unroll
    for (int p = 0; p < 4; ++p) acc[oc][p] = 0.f;
#pragma unroll
  for (int tap = 0; tap < 9; ++tap) {
    int ky = tap / 3, kx = tap % 3;
#pragma unroll
    for (int oc = 0; oc < 8; ++oc) {
      float wv = sW[tap * 8 + oc];
#pragma unroll
      for (int py = 0; py < 2; ++py)
#pragma unroll
        for (int px = 0; px < 2; ++px)
          acc[oc][py * 2 + px] += wv * win[(py + ky) * 4 + (px + kx)];
    }
  }
  if (y < 60) {
#pragma unroll
    for (int oc = 0; oc < 8; ++oc) {
      float m = fmaxf(fmaxf(acc[oc][0], acc[oc][1]), fmaxf(acc[oc][2], acc[oc][3])) + sB[oc];
      h1[(((size_t)b * 8 + oc) * 60 + y) * 80 + x] = fmaxf(m, 0.f);
    }
  }
}

// ================= K2: conv2(8->16)+relu+maxpool -> h2[B,16,30,40] =================
// grid (3,2,B*2), z = b*2 + ocgroup
__global__ __launch_bounds__(256) void k_conv2(
    const float* __restrict__ h1, const float* __restrict__ c2w,
    const float* __restrict__ c2b, float* __restrict__ h2) {
  __shared__ float sA[8][34][37];
  __shared__ __align__(16) float sW[576];  // [ic][tap][8 oc of group]
  __shared__ float sB[8];
  int b = blockIdx.z >> 1, ocg = blockIdx.z & 1;
  int ty0 = blockIdx.y * 16, tx0 = blockIdx.x * 16;
  int tid = threadIdx.x;
  for (int i = tid; i < 576; i += 256) {
    int ic = i / 72, tap = (i % 72) / 8, o = i % 8;
    sW[i] = c2w[(ocg * 8 + o) * 72 + ic * 9 + tap];
  }
  if (tid < 8) sB[tid] = c2b[ocg * 8 + tid];
  int iy0 = ty0 * 2 - 1, ix0 = tx0 * 2 - 1;
  const float* src = h1 + (size_t)b * 8 * 60 * 80;
  for (int idx = tid; idx < 8 * 34 * 34; idx += 256) {
    int ic = idx / (34 * 34), rc = idx % (34 * 34);
    int r = rc / 34, c = rc % 34;
    int gy = iy0 + r, gx = ix0 + c;
    float v = 0.f;
    if (gy >= 0 && gy < 60 && gx >= 0 && gx < 80) v = src[(ic * 60 + gy) * 80 + gx];
    sA[ic][r][c] = v;
  }
  __syncthreads();
  int ly = tid / 16, lx = tid % 16;
  int y = ty0 + ly, x = tx0 + lx;
  float acc[8][4];
#pragma unroll
  for (int oc = 0; oc < 8; ++oc)
#pragma unroll
    for (int p = 0; p < 4; ++p) acc[oc][p] = 0.f;
  const float4* sW4 = (const float4*)sW;
#pragma unroll 1
  for (int ic = 0; ic < 8; ++ic) {
    float win[16];
#pragma unroll
    for (int r = 0; r < 4; ++r)
#pragma unroll
      for (int c = 0; c < 4; ++c) win[r * 4 + c] = sA[ic][2 * ly + r][2 * lx + c];
#pragma unroll
    for (int tap = 0; tap < 9; ++tap) {
      int ky = tap / 3, kx = tap % 3;
#pragma unroll
      for (int q = 0; q < 2; ++q) {
        float4 w4v = sW4[(ic * 9 + tap) * 2 + q];
        float warr[4] = {w4v.x, w4v.y, w4v.z, w4v.w};
#pragma unroll
        for (int c4 = 0; c4 < 4; ++c4) {
          float wv = warr[c4];
          int oc = q * 4 + c4;
#pragma unroll
          for (int py = 0; py < 2; ++py)
#pragma unroll
            for (int px = 0; px < 2; ++px)
              acc[oc][py * 2 + px] += wv * win[(py + ky) * 4 + (px + kx)];
        }
      }
    }
  }
  if (y < 30 && x < 40) {
#pragma unroll
    for (int o = 0; o < 8; ++o) {
      int oc = ocg * 8 + o;
      float m = fmaxf(fmaxf(acc[o][0], acc[o][1]), fmaxf(acc[o][2], acc[o][3])) + sB[o];
      h2[(((size_t)b * 16 + oc) * 30 + y) * 40 + x] = fmaxf(m, 0.f);
    }
  }
}

// ================= K3: fc1 partial GEMM (K-split) =================
__global__ __launch_bounds__(256) void k_fc1_part(
    const float* __restrict__ h2, const float* __restrict__ f1w,
    float* __restrict__ fcpart) {
  __shared__ __align__(16) float sH[KS * 68];
  __shared__ __align__(16) float sWt[KS * 68];
  int sl = blockIdx.x, k0 = sl * KS;
  int tid = threadIdx.x;
  for (int idx = tid; idx < 64 * KS; idx += 256) {
    int b = idx / KS, kk = idx % KS;
    sH[kk * 68 + b] = h2[(size_t)b * 19200 + k0 + kk];
    sWt[kk * 68 + b] = f1w[(size_t)b * 19200 + k0 + kk];  // b plays the j role
  }
  __syncthreads();
  int bq = tid % 16, jq = tid / 16;
  int b0 = bq * 4, j0 = jq * 4;
  float acc[4][4];
#pragma unroll
  for (int i = 0; i < 4; ++i)
#pragma unroll
    for (int j = 0; j < 4; ++j) acc[i][j] = 0.f;
  for (int kk = 0; kk < KS; ++kk) {
    float4 hv = *(const float4*)&sH[kk * 68 + b0];
    float4 wv = *(const float4*)&sWt[kk * 68 + j0];
    float hb[4] = {hv.x, hv.y, hv.z, hv.w};
    float wb[4] = {wv.x, wv.y, wv.z, wv.w};
#pragma unroll
    for (int i = 0; i < 4; ++i)
#pragma unroll
      for (int j = 0; j < 4; ++j) acc[i][j] += hb[i] * wb[j];
  }
#pragma unroll
  for (int i = 0; i < 4; ++i)
#pragma unroll
    for (int j = 0; j < 4; ++j)
      fcpart[(size_t)sl * 4096 + (b0 + i) * 64 + (j0 + j)] = acc[i][j];
}

// ================= K4: per-batch fc1-reduce + head + jtr-reduce + solve =================
// grid: 64 blocks (one per b) x 256 threads
__global__ __launch_bounds__(256) void k_final(
    const float* __restrict__ fcpart, const float* __restrict__ f1b,
    const float* __restrict__ f2w, const float* __restrict__ f2b,
    const float* __restrict__ consts, const float* __restrict__ part,
    const float* __restrict__ JtJ, const float* __restrict__ poseR,
    const float* __restrict__ poseT, float* __restrict__ out) {
  __shared__ float sfc[4][64];
  __shared__ float fc1v[64];
  __shared__ float lg[6];
  __shared__ float lamv[6];
  __shared__ float jtrv[6];
  int b = blockIdx.x, tid = threadIdx.x;
  int g = tid >> 6, j = tid & 63;
  float a = 0.f;
  for (int s = g; s < NSLICE; s += 4) a += fcpart[(size_t)s * 4096 + b * 64 + j];
  sfc[g][j] = a;
  __syncthreads();
  if (tid < 64)
    fc1v[tid] = fmaxf(sfc[0][tid] + sfc[1][tid] + sfc[2][tid] + sfc[3][tid] + f1b[tid], 0.f);
  if (tid >= 64 && tid < 70) {  // jtr reduce on a different wave
    int i = tid - 64;
    float v = 0.f;
    for (int s = 0; s < SPLIT; ++s) v += part[(b * SPLIT + s) * 6 + i];
    jtrv[i] = v;
  }
  __syncthreads();
  if (tid < 6) {
    float v = f2b[tid];
#pragma unroll
    for (int k = 0; k < 64; ++k) v += fc1v[k] * f2w[tid * 64 + k];
    lg[tid] = v;
  }
  __syncthreads();
  if (tid < 6) {
    float m = lg[0];
#pragma unroll
    for (int i = 1; i < 6; ++i) m = fmaxf(m, lg[i]);
    float e[6], ssum = 0.f;
#pragma unroll
    for (int i = 0; i < 6; ++i) { e[i] = expf(lg[i] - m); ssum += e[i]; }
    float inv = 1.f / ssum;
    float wc = 0.f;
#pragma unroll
    for (int i = 0; i < 6; ++i) wc += (e[i] * inv) * consts[i * 6 + tid];
    float sg = 1.f / (1.f + expf(-wc));
    lamv[tid] = expf((-6.f + sg) * 2.302585092994046f);  // 10^(-6+sg)
  }
  __syncthreads();
  if (tid == 0) {
    float Hm[6][6];
    const float* srcH = JtJ + b * 36;
    float tr = 0.f;
#pragma unroll
    for (int i = 0; i < 6; ++i) {
#pragma unroll
      for (int jj = 0; jj < 6; ++jj) Hm[i][jj] = srcH[i * 6 + jj];
      tr += srcH[i * 6 + i];
    }
    float rhs[6];
#pragma unroll
    for (int i = 0; i < 6; ++i) {
      rhs[i] = jtrv[i];
      Hm[i][i] += lamv[i] + 1e-6f * tr + 1e-6f;
    }
    float L[6][6];
#pragma unroll
    for (int i = 0; i < 6; ++i) {
#pragma unroll
      for (int jj = 0; jj < 6; ++jj) {
        if (jj > i) continue;
        float s = Hm[i][jj];
#pragma unroll
        for (int k = 0; k < 6; ++k)
          if (k < jj) s -= L[i][k] * L[jj][k];
        if (i == jj) L[i][jj] = sqrtf(fmaxf(s, 1e-30f));
        else L[i][jj] = s / L[jj][jj];
      }
    }
    float yv[6];
#pragma unroll
    for (int i = 0; i < 6; ++i) {
      float s = rhs[i];
#pragma unroll
      for (int k = 0; k < 6; ++k)
        if (k < i) s -= L[i][k] * yv[k];
      yv[i] = s / L[i][i];
    }
    float xi[6];
#pragma unroll
    for (int ii = 5; ii >= 0; --ii) {
      float s = yv[ii];
#pragma unroll
      for (int k = 0; k < 6; ++k)
        if (k > ii) s -= L[k][ii] * xi[k];
      xi[ii] = s / L[ii][ii];
    }
    float wx = -xi[0], wy = -xi[1], wz = -xi[2];
    float th = fmaxf(sqrtf(wx * wx + wy * wy + wz * wz), 1e-12f);
    float ux = wx / th, uy = wy / th, uz = wz / th;
    float s = sinf(th), c1 = 1.f - cosf(th);
    float Rd[3][3];
    Rd[0][0] = 1.f + c1 * (ux * ux - 1.f);
    Rd[0][1] = -s * uz + c1 * (ux * uy);
    Rd[0][2] = s * uy + c1 * (ux * uz);
    Rd[1][0] = s * uz + c1 * (uy * ux);
    Rd[1][1] = 1.f + c1 * (uy * uy - 1.f);
    Rd[1][2] = -s * ux + c1 * (uy * uz);
    Rd[2][0] = -s * uy + c1 * (uz * ux);
    Rd[2][1] = s * ux + c1 * (uz * uy);
    Rd[2][2] = 1.f + c1 * (uz * uz - 1.f);
    float dt[3];
#pragma unroll
    for (int r = 0; r < 3; ++r)
      dt[r] = -(Rd[r][0] * xi[3] + Rd[r][1] * xi[4] + Rd[r][2] * xi[5]);
    const float* pR = poseR + b * 9;
    const float* pt = poseT + b * 3;
#pragma unroll
    for (int r = 0; r < 3; ++r) {
#pragma unroll
      for (int cc = 0; cc < 3; ++cc) {
        out[b * 12 + r * 4 + cc] =
            pR[r * 3 + 0] * Rd[0][cc] + pR[r * 3 + 1] * Rd[1][cc] + pR[r * 3 + 2] * Rd[2][cc];
      }
      out[b * 12 + r * 4 + 3] =
          pR[r * 3 + 0] * dt[0] + pR[r * 3 + 1] * dt[1] + pR[r * 3 + 2] * dt[2] + pt[r];
    }
  }
}

extern "C" void kernel_launch(void* const* d_in, const int* in_sizes, int n_in,
                              void* d_out, int out_size, void* d_ws, size_t ws_size,
                              hipStream_t stream) {
  const float* JtJ = (const float*)d_in[0];
  const float* Jt = (const float*)d_in[1];
  const float* wts = (const float*)d_in[2];
  const float* Rin = (const float*)d_in[3];
  const float* poseR = (const float*)d_in[4];
  const float* poseT = (const float*)d_in[5];
  const float* consts = (const float*)d_in[11];
  const float* c1w = (const float*)d_in[12];
  const float* c1b = (const float*)d_in[13];
  const float* c2w = (const float*)d_in[14];
  const float* c2b = (const float*)d_in[15];
  const float* f1w = (const float*)d_in[16];
  const float* f1b = (const float*)d_in[17];
  const float* f2w = (const float*)d_in[18];
  const float* f2b = (const float*)d_in[19];
  float* ws = (float*)d_ws;
  float* part = ws;                 // 12288
  float* h1 = part + 12288;         // 2457600
  float* h2 = h1 + 2457600;         // 1228800
  float* fcpart = h2 + 1228800;     // 819200
  float* out = (float*)d_out;

  k_front<<<dim3(NJTR + 1280), dim3(256), 0, stream>>>(Jt, wts, Rin, c1w, c1b, part, h1);
  k_conv2<<<dim3(3, 2, BATCH * 2), dim3(256), 0, stream>>>(h1, c2w, c2b, h2);
  k_fc1_part<<<dim3(NSLICE), dim3(256), 0, stream>>>(h2, f1w, fcpart);
  k_final<<<dim3(64), dim3(256), 0, stream>>>(fcpart, f1b, f2w, f2b, consts, part,
                                              JtJ, poseR, poseT, out);
}